// Round 2
// baseline (121.186 us; speedup 1.0000x reference)
//
#include <hip/hip_runtime.h>

typedef __attribute__((ext_vector_type(4))) int   int4v;
typedef __attribute__((ext_vector_type(4))) float float4v;

// XOR swizzle of the 16B slot within a 64B K-row: conflict-free-ish b128 reads.
__device__ __forceinline__ int swz(int row, int slot) {
    return slot ^ ((row ^ (row >> 2)) & 3);
}

// Exact replica of reference fake-quant grid index (IEEE div + round-half-even).
__device__ __forceinline__ int quant1(float x, float lo, float up, float scale) {
    float xc = fminf(fmaxf(x, lo), up);
    return (int)rintf((xc - lo) / scale);
}

__device__ __forceinline__ int qpack4(float4v v, float lo, float up, float sc) {
    return  quant1(v[0], lo, up, sc)        | (quant1(v[1], lo, up, sc) << 8) |
           (quant1(v[2], lo, up, sc) << 16) | (quant1(v[3], lo, up, sc) << 24);
}

__device__ __forceinline__ unsigned bsum(int p) {        // sum of 4 bytes (<=15 each)
    return ((unsigned)p * 0x01010101u) >> 24;
}

__global__ __launch_bounds__(256, 4) void qmm_kernel(
    const float* __restrict__ A, const float* __restrict__ B,
    const float* __restrict__ aLo, const float* __restrict__ aUp,
    const float* __restrict__ bLo, const float* __restrict__ bUp,
    float* __restrict__ Out)
{
    // qB: B^T as i8, [col 0..255][k 0..63] (K-contiguous per col), XOR-swizzled slots
    __shared__ int   qB[256 * 16];
    __shared__ float CBf[256];          // lA*sB * colsum(qB[j])

    const int tid = threadIdx.x;
    const int b   = blockIdx.x;

    const float lA = aLo[0], uA = aUp[0];
    const float lB = bLo[0], uB = bUp[0];
    const float sA  = (uA - lA) / 15.0f;
    const float sB  = (uB - lB) / 15.0f;
    const float sAB = sA * sB;

    const float4v* A4 = (const float4v*)(A + (size_t)b * 256 * 64);
    const float4v* B4 = (const float4v*)(B + (size_t)b * 64 * 256);
    float* outb = Out + (size_t)b * 256 * 256;

    // ---- stage B: thread (u=tid&63, w=tid>>6) owns cols 4u..4u+3, k w*16..w*16+15
    {
        const int u = tid & 63, w = tid >> 6;
        int pk[4][4];                                  // [col c][int slot m]
        #pragma unroll
        for (int m = 0; m < 4; ++m) {
            float4v r0 = __builtin_nontemporal_load(&B4[(size_t)(w*16 + m*4 + 0) * 64 + u]);
            float4v r1 = __builtin_nontemporal_load(&B4[(size_t)(w*16 + m*4 + 1) * 64 + u]);
            float4v r2 = __builtin_nontemporal_load(&B4[(size_t)(w*16 + m*4 + 2) * 64 + u]);
            float4v r3 = __builtin_nontemporal_load(&B4[(size_t)(w*16 + m*4 + 3) * 64 + u]);
            #pragma unroll
            for (int c = 0; c < 4; ++c) {
                pk[c][m] =  quant1(r0[c], lB, uB, sB)        | (quant1(r1[c], lB, uB, sB) << 8) |
                           (quant1(r2[c], lB, uB, sB) << 16) | (quant1(r3[c], lB, uB, sB) << 24);
            }
        }
        #pragma unroll
        for (int c = 0; c < 4; ++c) {
            int col = u * 4 + c;
            int4v v = {pk[c][0], pk[c][1], pk[c][2], pk[c][3]};
            *(int4v*)&qB[col * 16 + swz(col, w) * 4] = v;   // one b128, k-contiguous
        }
    }
    __syncthreads();                                   // qB ready

    // ---- col sums -> CBf[tid]
    {
        unsigned s = 0;
        #pragma unroll
        for (int sl = 0; sl < 4; ++sl) {
            int4v v = *(const int4v*)&qB[tid * 16 + swz(tid, sl) * 4];
            s += bsum(v[0]) + bsum(v[1]) + bsum(v[2]) + bsum(v[3]);
        }
        CBf[tid] = lA * sB * (float)s;
    }

    // ---- A fragments straight to registers (no LDS): lane owns rows wave*64+rt*16+lr,
    //      k-chunk lk*16..lk*16+15 (contiguous 64B per lane -> good coalescing)
    const int lane = tid & 63, wave = tid >> 6;
    const int lr = lane & 15, lk = lane >> 4;
    const float c64 = 64.0f * lA * lB;

    int4v afrag[4];
    float RA[4];
    #pragma unroll
    for (int rt = 0; rt < 4; ++rt) {
        int row = wave * 64 + rt * 16 + lr;
        const float4v* ap = A4 + (size_t)row * 16 + lk * 4;
        float4v x0 = __builtin_nontemporal_load(ap + 0);
        float4v x1 = __builtin_nontemporal_load(ap + 1);
        float4v x2 = __builtin_nontemporal_load(ap + 2);
        float4v x3 = __builtin_nontemporal_load(ap + 3);
        int p0 = qpack4(x0, lA, uA, sA), p1 = qpack4(x1, lA, uA, sA);
        int p2 = qpack4(x2, lA, uA, sA), p3 = qpack4(x3, lA, uA, sA);
        int4v f = {p0, p1, p2, p3};
        afrag[rt] = f;
        int rs = (int)(bsum(p0) + bsum(p1) + bsum(p2) + bsum(p3));
        rs += __shfl_xor(rs, 16);                      // reduce over lk (lane bits 4,5)
        rs += __shfl_xor(rs, 32);
        RA[rt] = sA * lB * (float)rs + c64;            // full 64*lA*lB constant here
    }
    __syncthreads();                                   // CBf ready

    // ---- compute: swapped operands -> lane holds row (wave*64+rt*16+lr),
    //      cols ct*16+lk*4..+3  => dwordx4 stores
    const int4v z4 = {0, 0, 0, 0};
    #pragma unroll 2
    for (int ct = 0; ct < 16; ++ct) {
        int col = ct * 16 + lr;
        int4v  bfrag = *(const int4v*)&qB[col * 16 + swz(col, lk) * 4];
        float4v cb   = *(const float4v*)&CBf[ct * 16 + lk * 4];
        #pragma unroll
        for (int rt = 0; rt < 4; ++rt) {
            int4v acc = __builtin_amdgcn_mfma_i32_16x16x64_i8(bfrag, afrag[rt], z4, 0, 0, 0);
            int row = wave * 64 + rt * 16 + lr;
            float4v o;
            o[0] = fmaf(sAB, (float)acc[0], RA[rt] + cb[0]);
            o[1] = fmaf(sAB, (float)acc[1], RA[rt] + cb[1]);
            o[2] = fmaf(sAB, (float)acc[2], RA[rt] + cb[2]);
            o[3] = fmaf(sAB, (float)acc[3], RA[rt] + cb[3]);
            __builtin_nontemporal_store(o, (float4v*)&outb[(size_t)row * 256 + ct * 16 + lk * 4]);
        }
    }
}

extern "C" void kernel_launch(void* const* d_in, const int* in_sizes, int n_in,
                              void* d_out, int out_size, void* d_ws, size_t ws_size,
                              hipStream_t stream) {
    const float* A   = (const float*)d_in[0];
    const float* B   = (const float*)d_in[1];
    const float* aLo = (const float*)d_in[2];
    const float* aUp = (const float*)d_in[3];
    const float* bLo = (const float*)d_in[4];
    const float* bUp = (const float*)d_in[5];
    float* Out = (float*)d_out;

    int batches = in_sizes[0] / (256 * 64);   // 128*8 = 1024
    qmm_kernel<<<batches, 256, 0, stream>>>(A, B, aLo, aUp, bLo, bUp, Out);
}